// Round 1
// baseline (291.362 us; speedup 1.0000x reference)
//
#include <hip/hip_runtime.h>

#define BB 16
#define NN 1024
#define ND 32
#define GC1 64
#define GC2 32
#define AUXD 128
#define ZD 16

// ---------------- K1: h1lin = node @ W1 + b1  (rows = B*N, out width 64)
__global__ __launch_bounds__(256) void k1(const float* __restrict__ node,
                                          const float* __restrict__ W1,
                                          const float* __restrict__ b1,
                                          float* __restrict__ h1lin) {
  __shared__ float W1s[ND][GC1];
  __shared__ float b1s[GC1];
  __shared__ float nds[4][ND];
  int t = threadIdx.x;
  for (int i = t; i < ND * GC1; i += 256) W1s[i / GC1][i % GC1] = W1[i];
  if (t < GC1) b1s[t] = b1[t];
  int row0 = blockIdx.x * 4;
  if (t < 4 * ND) nds[t / ND][t % ND] = node[(size_t)row0 * ND + t];
  __syncthreads();
  int r = t >> 6, d = t & 63;
  float acc = b1s[d];
#pragma unroll
  for (int k = 0; k < ND; ++k) acc += nds[r][k] * W1s[k][d];
  h1lin[(size_t)(row0 + r) * GC1 + d] = acc;
}

// ---------------- K2: stream adj_raw; a = sum(ch1..4); write adj_s; msg1 = a @ h1lin
#define TN1 16
#define TM1 256
__global__ __launch_bounds__(256) void k2(const float* __restrict__ adj_raw,
                                          const float* __restrict__ h1lin,
                                          float* __restrict__ adj_s,
                                          float* __restrict__ msg1,
                                          int store_adj) {
  __shared__ float a_s[TN1][TM1 + 4];
  int t = threadIdx.x;
  int blk = blockIdx.x;            // 1024 blocks: 64 per batch
  int b = blk >> 6;
  int n0 = (blk & 63) * TN1;
  const float* h1b = h1lin + (size_t)b * NN * GC1;
  int r = t >> 4;                  // 0..15 row
  int dg = t & 15;                 // d4 group
  float4 acc = make_float4(0.f, 0.f, 0.f, 0.f);
  for (int m0 = 0; m0 < NN; m0 += TM1) {
    __syncthreads();
#pragma unroll 4
    for (int i = 0; i < TN1; ++i) {
      const float* p = adj_raw + ((size_t)(b * NN + n0 + i) * NN + (m0 + t)) * 5;
      float a = p[1] + p[2] + p[3] + p[4];
      a_s[i][t] = a;
      if (store_adj) adj_s[(size_t)(b * NN + n0 + i) * NN + m0 + t] = a;
    }
    __syncthreads();
    for (int mm = 0; mm < TM1; mm += 4) {
      float4 av = *(const float4*)&a_s[r][mm];
      const float* hp = h1b + (size_t)(m0 + mm) * GC1 + dg * 4;
      float4 h0 = *(const float4*)(hp);
      float4 h1v = *(const float4*)(hp + GC1);
      float4 h2v = *(const float4*)(hp + 2 * GC1);
      float4 h3v = *(const float4*)(hp + 3 * GC1);
      acc.x += av.x * h0.x + av.y * h1v.x + av.z * h2v.x + av.w * h3v.x;
      acc.y += av.x * h0.y + av.y * h1v.y + av.z * h2v.y + av.w * h3v.y;
      acc.z += av.x * h0.z + av.y * h1v.z + av.z * h2v.z + av.w * h3v.z;
      acc.w += av.x * h0.w + av.y * h1v.w + av.z * h2v.w + av.w * h3v.w;
    }
  }
  float* mp = msg1 + ((size_t)(b * NN + n0 + r)) * GC1 + dg * 4;
  *(float4*)mp = acc;
}

// ---------------- K3: h2lin = (msg1 + h1lin) @ W2 + b2
__global__ __launch_bounds__(256) void k3(const float* __restrict__ msg1,
                                          const float* __restrict__ h1lin,
                                          const float* __restrict__ W2,
                                          const float* __restrict__ b2,
                                          float* __restrict__ h2lin) {
  __shared__ float W2s[GC1][GC2];
  __shared__ float b2s[GC2];
  __shared__ float xs[8][GC1];
  int t = threadIdx.x;
  for (int i = t; i < GC1 * GC2; i += 256) W2s[i / GC2][i % GC2] = W2[i];
  if (t < GC2) b2s[t] = b2[t];
  size_t base = (size_t)blockIdx.x * 8 * GC1;
  for (int i = t; i < 8 * GC1; i += 256) xs[i / GC1][i % GC1] = msg1[base + i] + h1lin[base + i];
  __syncthreads();
  int r = t >> 5, dd = t & 31;
  float acc = b2s[dd];
#pragma unroll
  for (int k = 0; k < GC1; ++k) acc += xs[r][k] * W2s[k][dd];
  h2lin[(size_t)(blockIdx.x * 8 + r) * GC2 + dd] = acc;
}

// ---------------- K4: h = adj_s @ h2lin + h2lin
#define TN2 32
#define TM2 256
template <bool FROM_RAW>
__global__ __launch_bounds__(256) void k4(const float* __restrict__ adj_src,
                                          const float* __restrict__ h2lin,
                                          float* __restrict__ hout) {
  __shared__ float a_s[TN2][TM2 + 4];
  int t = threadIdx.x;
  int blk = blockIdx.x;            // 512 blocks: 32 per batch
  int b = blk >> 5;
  int n0 = (blk & 31) * TN2;
  const float* h2b = h2lin + (size_t)b * NN * GC2;
  int r = t >> 3;                  // 0..31
  int dg = t & 7;                  // d4 group (32 wide)
  float4 acc = make_float4(0.f, 0.f, 0.f, 0.f);
  for (int m0 = 0; m0 < NN; m0 += TM2) {
    __syncthreads();
    if (FROM_RAW) {
#pragma unroll 4
      for (int i = 0; i < TN2; ++i) {
        const float* p = adj_src + ((size_t)(b * NN + n0 + i) * NN + (m0 + t)) * 5;
        a_s[i][t] = p[1] + p[2] + p[3] + p[4];
      }
    } else {
#pragma unroll 8
      for (int i = 0; i < TN2; ++i) {
        a_s[i][t] = adj_src[(size_t)(b * NN + n0 + i) * NN + m0 + t];
      }
    }
    __syncthreads();
    for (int mm = 0; mm < TM2; mm += 4) {
      float4 av = *(const float4*)&a_s[r][mm];
      const float* hp = h2b + (size_t)(m0 + mm) * GC2 + dg * 4;
      float4 h0 = *(const float4*)(hp);
      float4 h1v = *(const float4*)(hp + GC2);
      float4 h2v = *(const float4*)(hp + 2 * GC2);
      float4 h3v = *(const float4*)(hp + 3 * GC2);
      acc.x += av.x * h0.x + av.y * h1v.x + av.z * h2v.x + av.w * h3v.x;
      acc.y += av.x * h0.y + av.y * h1v.y + av.z * h2v.y + av.w * h3v.y;
      acc.z += av.x * h0.z + av.y * h1v.z + av.z * h2v.z + av.w * h3v.z;
      acc.w += av.x * h0.w + av.y * h1v.w + av.z * h2v.w + av.w * h3v.w;
    }
  }
  size_t row = (size_t)(b * NN + n0 + r);
  float4 sv = *(const float4*)(h2lin + row * GC2 + dg * 4);
  acc.x += sv.x; acc.y += sv.y; acc.z += sv.z; acc.w += sv.w;
  *(float4*)(hout + row * GC2 + dg * 4) = acc;
}

// ---------------- K5: gate = sigmoid(x@Ws+bs)*tanh(x@Wt+bt); partial node-sum per block
#define TR 32
__global__ __launch_bounds__(256) void k5(const float* __restrict__ h,
                                          const float* __restrict__ node,
                                          const float* __restrict__ Ws,
                                          const float* __restrict__ bs,
                                          const float* __restrict__ Wt,
                                          const float* __restrict__ bt,
                                          float* __restrict__ partials) {
  __shared__ float xs[TR][GC2 + ND];   // 32 x 64
  __shared__ float red[2][AUXD];
  int t = threadIdx.x;
  int blk = blockIdx.x;                // 512 blocks: 32 per batch
  int b = blk >> 5;
  int n0 = (blk & 31) * TR;
  for (int i = t; i < TR * GC2; i += 256) {
    int rr = i >> 5, kk = i & 31;
    xs[rr][kk] = h[((size_t)(b * NN + n0 + rr)) * GC2 + kk];
  }
  for (int i = t; i < TR * ND; i += 256) {
    int rr = i >> 5, kk = i & 31;
    xs[rr][GC2 + kk] = node[((size_t)(b * NN + n0 + rr)) * ND + kk];
  }
  int c = t & 127;
  int g = t >> 7;
  float wsc[64], wtc[64];
#pragma unroll
  for (int k = 0; k < 64; ++k) {
    wsc[k] = Ws[(size_t)k * AUXD + c];
    wtc[k] = Wt[(size_t)k * AUXD + c];
  }
  float bsv = bs[c], btv = bt[c];
  __syncthreads();
  float part = 0.f;
  for (int rr = g * (TR / 2); rr < (g + 1) * (TR / 2); ++rr) {
    float as_ = bsv, at_ = btv;
#pragma unroll
    for (int k = 0; k < 64; ++k) {
      float xv = xs[rr][k];
      as_ += xv * wsc[k];
      at_ += xv * wtc[k];
    }
    float sg = 1.f / (1.f + __expf(-as_));
    float e2 = __expf(2.f * at_);
    float th = 1.f - 2.f / (e2 + 1.f);
    part += sg * th;
  }
  red[g][c] = part;
  __syncthreads();
  if (t < AUXD) {
    partials[(size_t)blk * AUXD + t] = red[0][t] + red[1][t];
  }
}

// ---------------- K6: reduce partials, tanh, MLP(128->128->128)->head(16)
__global__ __launch_bounds__(128) void k6(const float* __restrict__ partials,
                                          const float* __restrict__ Wm1, const float* __restrict__ bm1,
                                          const float* __restrict__ Wm2, const float* __restrict__ bm2,
                                          const float* __restrict__ Wl, const float* __restrict__ bl,
                                          float* __restrict__ out) {
  __shared__ float g_s[AUXD];
  __shared__ float g2_s[AUXD];
  int t = threadIdx.x;
  int b = blockIdx.x;
  float s = 0.f;
  for (int j = 0; j < 32; ++j) s += partials[((size_t)(b * 32 + j)) * AUXD + t];
  float e2 = __expf(2.f * s);
  g_s[t] = 1.f - 2.f / (e2 + 1.f);
  __syncthreads();
  float acc = bm1[t];
#pragma unroll 16
  for (int k = 0; k < AUXD; ++k) acc += g_s[k] * Wm1[(size_t)k * 128 + t];
  e2 = __expf(2.f * acc);
  g2_s[t] = 1.f - 2.f / (e2 + 1.f);
  __syncthreads();
  acc = bm2[t];
#pragma unroll 16
  for (int k = 0; k < 128; ++k) acc += g2_s[k] * Wm2[(size_t)k * 128 + t];
  e2 = __expf(2.f * acc);
  float g3 = 1.f - 2.f / (e2 + 1.f);
  __syncthreads();
  g_s[t] = g3;
  __syncthreads();
  if (t < ZD) {
    float a = bl[t];
#pragma unroll 16
    for (int k = 0; k < 128; ++k) a += g_s[k] * Wl[(size_t)k * ZD + t];
    out[(size_t)b * ZD + t] = a;
  }
}

extern "C" void kernel_launch(void* const* d_in, const int* in_sizes, int n_in,
                              void* d_out, int out_size, void* d_ws, size_t ws_size,
                              hipStream_t stream) {
  const float* node = (const float*)d_in[0];
  const float* adj_raw = (const float*)d_in[1];
  const float* W1 = (const float*)d_in[2];
  const float* b1 = (const float*)d_in[3];
  const float* W2 = (const float*)d_in[4];
  const float* b2 = (const float*)d_in[5];
  const float* Ws = (const float*)d_in[6];
  const float* bs = (const float*)d_in[7];
  const float* Wt = (const float*)d_in[8];
  const float* bt = (const float*)d_in[9];
  const float* Wm1 = (const float*)d_in[10];
  const float* bm1 = (const float*)d_in[11];
  const float* Wm2 = (const float*)d_in[12];
  const float* bm2 = (const float*)d_in[13];
  const float* Wl = (const float*)d_in[14];
  const float* bl = (const float*)d_in[15];
  float* out = (float*)d_out;
  float* ws = (float*)d_ws;

  size_t o_h1 = 0;
  size_t o_msg1 = o_h1 + (size_t)BB * NN * GC1;       // 1,048,576
  size_t o_h2 = o_msg1 + (size_t)BB * NN * GC1;       // 2,097,152
  size_t o_h = o_h2 + (size_t)BB * NN * GC2;          // 2,621,440
  size_t o_part = o_h + (size_t)BB * NN * GC2;        // 3,145,728
  size_t o_adj = o_part + (size_t)512 * AUXD;         // 3,211,264
  size_t need_bytes = (o_adj + (size_t)BB * NN * NN) * sizeof(float);
  bool store = (ws_size >= need_bytes);

  float* h1lin = ws + o_h1;
  float* msg1 = ws + o_msg1;
  float* h2lin = ws + o_h2;
  float* hbuf = ws + o_h;
  float* part = ws + o_part;
  float* adj_s = ws + o_adj;

  k1<<<4096, 256, 0, stream>>>(node, W1, b1, h1lin);
  k2<<<1024, 256, 0, stream>>>(adj_raw, h1lin, adj_s, msg1, store ? 1 : 0);
  k3<<<2048, 256, 0, stream>>>(msg1, h1lin, W2, b2, h2lin);
  if (store) {
    k4<false><<<512, 256, 0, stream>>>(adj_s, h2lin, hbuf);
  } else {
    k4<true><<<512, 256, 0, stream>>>(adj_raw, h2lin, hbuf);
  }
  k5<<<512, 256, 0, stream>>>(hbuf, node, Ws, bs, Wt, bt, part);
  k6<<<16, 128, 0, stream>>>(part, Wm1, bm1, Wm2, bm2, Wl, bl, out);
}